// Round 3
// baseline (118.369 us; speedup 1.0000x reference)
//
#include <hip/hip_runtime.h>
#include <math.h>

#define TPB 512

// ---------------------------------------------------------------------------
// Prep kernel: fused weight table wq[hw*128+c] = {bw0, bw1, bw2, patc},
// patc = sum_{k: psi[k]==c} pat_w[hw*32+k]. (pat head is linear in feats.)
// ---------------------------------------------------------------------------
__global__ __launch_bounds__(256)
void prep_weights(const float* __restrict__ base_w,  // [131072,3]
                  const float* __restrict__ pat_w,   // [32768]
                  const int*   __restrict__ psi,     // [32]
                  float4* __restrict__ wq)           // [131072]
{
    int idx = blockIdx.x * 256 + threadIdx.x;        // 0..131071
    int hw = idx >> 7, c = idx & 127;
    const float* bp = base_w + (size_t)idx * 3;
    float b0 = bp[0], b1 = bp[1], b2 = bp[2];
    float pc = 0.f;
    const float* pr = pat_w + hw * 32;
    #pragma unroll
    for (int k = 0; k < 32; ++k)
        pc += (psi[k] == c) ? pr[k] : 0.f;
    wq[idx] = make_float4(b0, b1, b2, pc);
}

// ---------------------------------------------------------------------------
// Main kernel: 4 blocks per sample (quarter = 8 output rows), 512 threads.
// Thread owns ONE channel c = tid&127 (w[27] resident in regs, <=64 VGPR via
// launch_bounds(512,8) -> 8 waves/SIMD, 4 blocks/CU = 32 waves/CU).
// sg = tid>>7 in [0,4) covers the 64 (oh_loc,q) slots over 16 iterations.
// Writes 5 partial head-sums per block to ws; finalize kernel routes.
// ---------------------------------------------------------------------------
__global__ __launch_bounds__(TPB, 8)
void pattern_branch_kernel(const float* __restrict__ in,      // [B,64,64,3]
                           const float* __restrict__ conv_w,  // [27,128]
                           const float* __restrict__ conv_b,  // [128]
                           const float* __restrict__ match_w, // [128]
                           const float4* __restrict__ wq,     // [131072]
                           float* __restrict__ part)          // [4][5][256]
{
    constexpr int ROWF4 = 50;              // float4 per padded row
    __shared__ float4 xlds4[17 * ROWF4];   // 13.6 KB: input rows for this quarter
    __shared__ float  red[8][5];

    const int bx  = blockIdx.x;
    const int qh  = bx >> 8;               // quarter 0..3 (grid = qh*256 + b)
    const int b   = bx & 255;
    const int tid = threadIdx.x;

    // ---- stage 17 input rows (ih = 16*qh .. 16*qh+16), zero-pad row 64/col 64
    for (int s = tid; s < 17 * ROWF4; s += TPB) xlds4[s] = make_float4(0.f, 0.f, 0.f, 0.f);
    __syncthreads();
    const float4* inp4 = (const float4*)(in + (size_t)b * 12288);
    for (int s = tid; s < 17 * 48; s += TPB) {
        int r  = s / 48;
        int qq = s - r * 48;
        int ih = 16 * qh + r;
        if (ih < 64) xlds4[r * ROWF4 + qq] = inp4[ih * 48 + qq];
    }
    __syncthreads();

    // ---- per-thread conv weights: one channel
    const int c  = tid & 127;
    const int sg = tid >> 7;               // 0..3
    float w[27];
    #pragma unroll
    for (int k = 0; k < 27; ++k) w[k] = conv_w[k * 128 + c];
    const float bias = conv_b[c];
    const float mw   = match_w[c];

    float s_match = 0.f, sb0 = 0.f, sb1 = 0.f, sb2 = 0.f, s_pat = 0.f;

    // ---- main loop: 16 iters x (4 ow x 1 ch); LDS reads are wave-broadcast
    for (int it = 0; it < 16; ++it) {
        int slot   = it * 4 + sg;          // 0..63 = (oh_loc:8) x (q:8)
        int oh_loc = slot >> 3;
        int q      = slot & 7;             // ow = 4q+v
        float acc[4] = { bias, bias, bias, bias };

        #pragma unroll
        for (int kh = 0; kh < 3; ++kh) {
            const float4* rp = &xlds4[(2 * oh_loc + kh) * ROWF4 + 6 * q];
            // first half: floats 0..15 of the 27-float window -> v=0 (0..8), v=1 (6..14)
            {
                float4 t0 = rp[0], t1 = rp[1], t2 = rp[2], t3 = rp[3];
                float x[16] = { t0.x,t0.y,t0.z,t0.w, t1.x,t1.y,t1.z,t1.w,
                                t2.x,t2.y,t2.z,t2.w, t3.x,t3.y,t3.z,t3.w };
                #pragma unroll
                for (int t9 = 0; t9 < 9; ++t9) {
                    float wk = w[kh * 9 + t9];
                    acc[0] = fmaf(x[t9],     wk, acc[0]);
                    acc[1] = fmaf(x[6 + t9], wk, acc[1]);
                }
            }
            // second half: floats 12..27 -> v=2 (12..20), v=3 (18..26)
            {
                float4 t0 = rp[3], t1 = rp[4], t2 = rp[5], t3 = rp[6];
                float x[16] = { t0.x,t0.y,t0.z,t0.w, t1.x,t1.y,t1.z,t1.w,
                                t2.x,t2.y,t2.z,t2.w, t3.x,t3.y,t3.z,t3.w };
                #pragma unroll
                for (int t9 = 0; t9 < 9; ++t9) {
                    float wk = w[kh * 9 + t9];
                    acc[2] = fmaf(x[t9],     wk, acc[2]);
                    acc[3] = fmaf(x[6 + t9], wk, acc[3]);
                }
            }
        }
        // epilogue: fused head weights, coalesced float4 per v
        int hwbase = (8 * qh + oh_loc) * 32 + 4 * q;
        #pragma unroll
        for (int v = 0; v < 4; ++v) {
            float fv = fmaxf(acc[v], 0.f);
            float4 wv = wq[(size_t)(hwbase + v) * 128 + c];
            s_match = fmaf(mw, fv, s_match);
            sb0   = fmaf(fv, wv.x, sb0);
            sb1   = fmaf(fv, wv.y, sb1);
            sb2   = fmaf(fv, wv.z, sb2);
            s_pat = fmaf(fv, wv.w, s_pat);
        }
    }

    // ---- block reduction: wave shuffle, then LDS across 8 waves
    float vals[5] = { s_match, sb0, sb1, sb2, s_pat };
    #pragma unroll
    for (int off = 32; off > 0; off >>= 1)
        #pragma unroll
        for (int v = 0; v < 5; ++v)
            vals[v] += __shfl_down(vals[v], off, 64);
    int wv = tid >> 6, lane = tid & 63;
    if (lane == 0) {
        #pragma unroll
        for (int v = 0; v < 5; ++v) red[wv][v] = vals[v];
    }
    __syncthreads();
    if (tid == 0) {
        #pragma unroll
        for (int v = 0; v < 5; ++v) {
            float t = 0.f;
            for (int wj = 0; wj < 8; ++wj) t += red[wj][v];
            part[(qh * 5 + v) * 256 + b] = t;
        }
    }
}

// ---------------------------------------------------------------------------
// Finalize: one block, thread b sums the 4 quarter-partials and routes.
// ---------------------------------------------------------------------------
__global__ __launch_bounds__(256)
void finalize_kernel(const float* __restrict__ part,    // [4][5][256]
                     const float* __restrict__ match_b,
                     const float* __restrict__ pat_b,
                     const float* __restrict__ base_b,
                     float* __restrict__ out)           // [B,3]
{
    int b = threadIdx.x;
    float t[5] = { 0.f, 0.f, 0.f, 0.f, 0.f };
    #pragma unroll
    for (int j = 0; j < 4; ++j)
        #pragma unroll
        for (int v = 0; v < 5; ++v)
            t[v] += part[(j * 5 + v) * 256 + b];
    float score = t[0] * (1.f / 1024.f) + match_b[0];
    float p = 1.f / (1.f + expf(-(t[4] + pat_b[0])));
    float l0 = t[1] + base_b[0], l1 = t[2] + base_b[1], l2 = t[3] + base_b[2];
    float m = fmaxf(l0, fmaxf(l1, l2));
    float e0 = expf(l0 - m), e1 = expf(l1 - m), e2 = expf(l2 - m);
    float inv = 1.f / (e0 + e1 + e2);
    bool use_pat = (score > 0.f) && (p >= 0.5f);
    float o0, o1, o2;
    if (use_pat) { o0 = p; o1 = 0.5f * (1.f - p); o2 = o1; }
    else         { o0 = e0 * inv; o1 = e1 * inv; o2 = e2 * inv; }
    out[b * 3 + 0] = o0;
    out[b * 3 + 1] = o1;
    out[b * 3 + 2] = o2;
}

extern "C" void kernel_launch(void* const* d_in, const int* in_sizes, int n_in,
                              void* d_out, int out_size, void* d_ws, size_t ws_size,
                              hipStream_t stream) {
    const float* in      = (const float*)d_in[0];
    const float* conv_w  = (const float*)d_in[1];
    const float* conv_b  = (const float*)d_in[2];
    const float* match_w = (const float*)d_in[3];
    const float* match_b = (const float*)d_in[4];
    const float* pat_w   = (const float*)d_in[5];
    const float* pat_b   = (const float*)d_in[6];
    const float* base_w  = (const float*)d_in[7];
    const float* base_b  = (const float*)d_in[8];
    const int*   psi     = (const int*)d_in[9];
    float* out = (float*)d_out;

    float4* wq   = (float4*)d_ws;                       // 2 MB
    float*  part = (float*)((char*)d_ws + (size_t)131072 * 16);  // 4*5*256 floats

    prep_weights<<<512, 256, 0, stream>>>(base_w, pat_w, psi, wq);

    int B = in_sizes[0] / (64 * 64 * 3);   // 256
    pattern_branch_kernel<<<4 * B, TPB, 0, stream>>>(
        in, conv_w, conv_b, match_w, wq, part);

    finalize_kernel<<<1, 256, 0, stream>>>(part, match_b, pat_b, base_b, out);
}